// Round 8
// baseline (150.639 us; speedup 1.0000x reference)
//
#include <hip/hip_runtime.h>
#include <hip/hip_cooperative_groups.h>
#include <stdint.h>

#define BB 512
#define NN 8192
#define KK 16
#define HH 16

typedef _Float16 f16;
typedef _Float16 f16x4 __attribute__((ext_vector_type(4)));
typedef float f32x4 __attribute__((ext_vector_type(4)));

namespace cg = cooperative_groups;

// ---------------------------------------------------------------------------
// Fused cooperative kernel, grid = 1024 x 512thr (4 blocks/CU, exact fit).
// Phase 1 (blocks 0..255): pack signs of x into xpT[j*16+w] (512 KB, L2);
//   coalesced x reads (32-j lanes), LDS-staged contiguous 2KB writes.
// All blocks concurrently: stage own 16KB W1 slice -> LDS (overlaps pack's
//   x stream), build f16 A-frags in-register, pre-load neighs.
// grid.sync()
// Phase 2 (all 1024 blocks = 512 n-stripes x 2 b-halves): R7's proven loop:
//   per wave 2n x 256b, sign-word gather (dwordx2/lane), wave-private LDS
//   wbuf, B-frag = bit -> +-1.0f16, mfma_f32_16x16x16_f16, relu-dot to zbuf,
//   dense sigmoid pass, fused output transpose via LDS tile.
// LDS: union{pack stage 2.2K, W1 stage 16K, out tile 20K} + wbuf 5K + zbuf 8K
//   = 33.8 KB -> 4 blocks/CU; launch_bounds(512,8) targets <=64 VGPR.
// ---------------------------------------------------------------------------
__global__ __launch_bounds__(512, 8) void fused_kernel(
    const float* __restrict__ x, const int* __restrict__ neighs,
    const float* __restrict__ W1, const float* __restrict__ b1,
    const float* __restrict__ W2, const float* __restrict__ b2,
    uint32_t* __restrict__ xpT, float* __restrict__ out) {
    __shared__ __align__(16) union SMem {
        uint32_t pstage[32 * 17];   // phase-1 pack staging
        float    w1s[16 * 256];     // W1 slice (prologue)
        float    tile[256 * 20];    // output transpose tile (epilogue)
    } usm;
    __shared__ __align__(16) uint32_t wbuf[8][8 * 20];  // [wave][w*20+k]
    __shared__ __align__(16) float zbuf[8][64][4];      // [wave][t*16+b16][lg]

    const int tid = threadIdx.x;
    const int bid = blockIdx.x;

    // ---------------- phase 1: pack (blocks 0..255 only) ----------------
    if (bid < 256) {
        const int j0 = bid * 32;
        const int jl = tid & 31;     // 32 consecutive j -> coalesced reads
        const int wq = tid >> 5;     // word group 0..15
        uint32_t word = 0u;
#pragma unroll
        for (int i = 0; i < 32; ++i)
            word |= (x[(size_t)(wq * 32 + i) * NN + j0 + jl] > 0.0f ? 1u : 0u)
                    << i;
        usm.pstage[jl * 17 + wq] = word;
        __syncthreads();
        // contiguous 2KB write: xpT[j0*16 .. j0*16+512)
        xpT[(size_t)j0 * 16 + tid] = usm.pstage[(tid >> 4) * 17 + (tid & 15)];
        __threadfence();
        __syncthreads();   // pstage dead before w1s writes
    }

    // ---------------- all blocks: W1 stage + A-frags + aux loads --------
    const int wv  = tid >> 6;        // 0..7
    const int l   = tid & 63;
    const int l15 = l & 15;
    const int lg  = l >> 4;          // 0..3
    const int n0  = (bid >> 1) * 16;
    const int half = bid & 1;
    const int b0  = half * 256;
    const int w0  = half * 8;
    const int nA  = n0 + wv * 2;
    const int nB  = nA + 1;

    {   // 16 n x 256 f32 = 16 KB, coalesced float4
        const float4* src = (const float4*)(W1 + (size_t)n0 * (KK * HH));
        float4* dst = (float4*)usm.w1s;
        dst[tid]       = src[tid];
        dst[tid + 512] = src[tid + 512];
    }
    const int j0g = neighs[nA * KK + l15];   // 64B broadcast loads
    const int j1g = neighs[nB * KK + l15];
    __syncthreads();

    f16x4 aA, aB;
#pragma unroll
    for (int i = 0; i < 4; ++i)
        aA[i] = (f16)usm.w1s[(wv * 2) * 256 + (lg * 4 + i) * 16 + l15];
#pragma unroll
    for (int i = 0; i < 4; ++i)
        aB[i] = (f16)usm.w1s[(wv * 2 + 1) * 256 + (lg * 4 + i) * 16 + l15];
    __syncthreads();   // w1s dead -> tile may be written

    // ---------------- grid-wide barrier: xpT complete -------------------
    cg::this_grid().sync();

    // ---------------- phase 2: gather + MFMA loop (R7 structure) --------
    const uint2 g0 = *(const uint2*)&xpT[(size_t)j0g * 16 + w0 + lg * 2];
    const uint2 g1 = *(const uint2*)&xpT[(size_t)j1g * 16 + w0 + lg * 2];

#pragma unroll
    for (int ni = 0; ni < 2; ++ni) {
        const int n = ni ? nB : nA;
        const uint2 g = ni ? g1 : g0;
        const f16x4 a = ni ? aB : aA;
        const int nloc = wv * 2 + ni;

        // stage this ni's sign words (wave-private, no barrier)
        wbuf[wv][(2 * lg) * 20 + l15]     = g.x;
        wbuf[wv][(2 * lg + 1) * 20 + l15] = g.y;

        const float4 b1v = *(const float4*)(b1 + (size_t)n * HH + lg * 4);
        const f32x4 cinit = {b1v.x, b1v.y, b1v.z, b1v.w};
        const float4 w2v = *(const float4*)(W2 + (size_t)n * HH + lg * 4);
        const float b2n = b2[n];

#pragma unroll
        for (int g4 = 0; g4 < 4; ++g4) {   // 4 groups x 4 tiles
#pragma unroll
            for (int t = 0; t < 4; ++t) {
                const int tb = g4 * 4 + t;
                const int wg = tb >> 1;
                const uint4 wk = *(const uint4*)&wbuf[wv][wg * 20 + lg * 4];
                const int pos = (tb & 1) * 16 + l15;
                // bit=1 -> +1.0f16 (0x3C00), bit=0 -> -1.0f16 (0xBC00)
                const uint32_t d0 = 0xBC00BC00u ^ (((wk.x >> pos) & 1u) << 15) ^
                                    ((wk.y >> pos) << 31);
                const uint32_t d1 = 0xBC00BC00u ^ (((wk.z >> pos) & 1u) << 15) ^
                                    ((wk.w >> pos) << 31);
                uint2 bdu; bdu.x = d0; bdu.y = d1;
                const f16x4 bfr = __builtin_bit_cast(f16x4, bdu);

                const f32x4 acc = __builtin_amdgcn_mfma_f32_16x16x16f16(
                    a, bfr, cinit, 0, 0, 0);

                const float zp =
                    fmaf(fmaxf(acc[0], 0.f), w2v.x,
                    fmaf(fmaxf(acc[1], 0.f), w2v.y,
                    fmaf(fmaxf(acc[2], 0.f), w2v.z,
                         fmaxf(acc[3], 0.f) * w2v.w)));
                zbuf[wv][t * 16 + l15][lg] = zp;
            }
            // dense pass: 64 lanes = 64 outputs of this 4-tile group
            const f32x4 v = *(const f32x4*)&zbuf[wv][l][0];
            const float z = (v[0] + v[1]) + (v[2] + v[3]) + b2n;
            const float r = __builtin_amdgcn_rcpf(1.0f + __expf(-z));
            usm.tile[(g4 * 64 + l) * 20 + nloc] = r;
        }
    }
    __syncthreads();

    // full-line stores: 4 lanes cover one 64B row of out[b][n0..n0+15]
#pragma unroll
    for (int p = 0; p < 2; ++p) {
        const int row = (tid >> 2) + p * 128;
        const int c   = (tid & 3) * 4;
        const float4 v = *(const float4*)&usm.tile[row * 20 + c];
        *(float4*)(out + (size_t)(b0 + row) * NN + n0 + c) = v;
    }
}

// ===========================================================================
// Fallback path (R7): separate prep + mfma kernels, used if cooperative
// launch is rejected.  Identical math.
// ===========================================================================
__global__ __launch_bounds__(256) void prep_kernel(
    const float* __restrict__ x, const float* __restrict__ W1,
    uint32_t* __restrict__ xpT, uint2* __restrict__ W1f) {
    const int bid = blockIdx.x;
    const int tid = threadIdx.x;
    if (bid < 512) {
        const int j = (bid & 31) * 256 + tid;
        const int w = bid >> 5;
        uint32_t word = 0u;
#pragma unroll
        for (int i = 0; i < 32; ++i)
            word |= (x[(size_t)(w * 32 + i) * NN + j] > 0.0f ? 1u : 0u) << i;
        xpT[(size_t)j * 16 + w] = word;
    } else {
        const int n   = (bid - 512) * 4 + (tid >> 6);
        const int l   = tid & 63;
        const int l15 = l & 15;
        const int lg  = l >> 4;
        const float* W1n = W1 + (size_t)n * (KK * HH) + lg * 4 * HH + l15;
        f16x4 a;
#pragma unroll
        for (int i = 0; i < 4; ++i) a[i] = (f16)W1n[i * HH];
        W1f[(size_t)n * 64 + l] = __builtin_bit_cast(uint2, a);
    }
}

__global__ __launch_bounds__(512, 8) void mfma_kernel(
    const uint32_t* __restrict__ xpT, const uint2* __restrict__ W1f,
    const int* __restrict__ neighs, const float* __restrict__ b1,
    const float* __restrict__ W2, const float* __restrict__ b2,
    float* __restrict__ out) {
    __shared__ __align__(16) uint32_t wbuf[8][8 * 20];
    __shared__ __align__(16) float zbuf[8][64][4];
    __shared__ __align__(16) float tile[256][20];

    const int tid = threadIdx.x;
    const int wv  = tid >> 6;
    const int l   = tid & 63;
    const int l15 = l & 15;
    const int lg  = l >> 4;
    const int n0  = blockIdx.x * 16;
    const int b0  = blockIdx.y * 256;
    const int w0  = blockIdx.y * 8;

    const int nA = n0 + wv * 2;
    const int nB = nA + 1;

    const int j0 = neighs[nA * KK + l15];
    const int j1 = neighs[nB * KK + l15];
    const uint2 g0 = *(const uint2*)&xpT[(size_t)j0 * 16 + w0 + lg * 2];
    const uint2 g1 = *(const uint2*)&xpT[(size_t)j1 * 16 + w0 + lg * 2];
    const uint2 af0u = W1f[(size_t)nA * 64 + l];
    const uint2 af1u = W1f[(size_t)nB * 64 + l];

#pragma unroll
    for (int ni = 0; ni < 2; ++ni) {
        const int n = ni ? nB : nA;
        const uint2 g = ni ? g1 : g0;
        const f16x4 a = __builtin_bit_cast(f16x4, ni ? af1u : af0u);
        const int nloc = wv * 2 + ni;

        wbuf[wv][(2 * lg) * 20 + l15]     = g.x;
        wbuf[wv][(2 * lg + 1) * 20 + l15] = g.y;

        const float4 b1v = *(const float4*)(b1 + (size_t)n * HH + lg * 4);
        const f32x4 cinit = {b1v.x, b1v.y, b1v.z, b1v.w};
        const float4 w2v = *(const float4*)(W2 + (size_t)n * HH + lg * 4);
        const float b2n = b2[n];

#pragma unroll
        for (int g4 = 0; g4 < 4; ++g4) {
#pragma unroll
            for (int t = 0; t < 4; ++t) {
                const int tb = g4 * 4 + t;
                const int wg = tb >> 1;
                const uint4 wk = *(const uint4*)&wbuf[wv][wg * 20 + lg * 4];
                const int pos = (tb & 1) * 16 + l15;
                const uint32_t d0 = 0xBC00BC00u ^ (((wk.x >> pos) & 1u) << 15) ^
                                    ((wk.y >> pos) << 31);
                const uint32_t d1 = 0xBC00BC00u ^ (((wk.z >> pos) & 1u) << 15) ^
                                    ((wk.w >> pos) << 31);
                uint2 bdu; bdu.x = d0; bdu.y = d1;
                const f16x4 bfr = __builtin_bit_cast(f16x4, bdu);
                const f32x4 acc = __builtin_amdgcn_mfma_f32_16x16x16f16(
                    a, bfr, cinit, 0, 0, 0);
                const float zp =
                    fmaf(fmaxf(acc[0], 0.f), w2v.x,
                    fmaf(fmaxf(acc[1], 0.f), w2v.y,
                    fmaf(fmaxf(acc[2], 0.f), w2v.z,
                         fmaxf(acc[3], 0.f) * w2v.w)));
                zbuf[wv][t * 16 + l15][lg] = zp;
            }
            const f32x4 v = *(const f32x4*)&zbuf[wv][l][0];
            const float z = (v[0] + v[1]) + (v[2] + v[3]) + b2n;
            const float r = __builtin_amdgcn_rcpf(1.0f + __expf(-z));
            tile[g4 * 64 + l][nloc] = r;
        }
    }
    __syncthreads();

#pragma unroll
    for (int p = 0; p < 2; ++p) {
        const int row = (tid >> 2) + p * 128;
        const int c   = (tid & 3) * 4;
        const float4 v = *(const float4*)&tile[row][c];
        *(float4*)(out + (size_t)(b0 + row) * NN + n0 + c) = v;
    }
}

__global__ __launch_bounds__(512) void scalar_kernel(
    const float* __restrict__ x, const int* __restrict__ neighs,
    const float* __restrict__ W1, const float* __restrict__ b1,
    const float* __restrict__ W2, const float* __restrict__ b2,
    float* __restrict__ outp) {
    const int n = blockIdx.x;
    const int b = threadIdx.x;
    const int* nb = neighs + n * KK;
    const float* W1n = W1 + (size_t)n * KK * HH;
    const float* b1n = b1 + (size_t)n * HH;
    const float* W2n = W2 + (size_t)n * HH;

    float s[KK];
#pragma unroll
    for (int k = 0; k < KK; ++k) s[k] = x[(size_t)b * NN + nb[k]];

    float acc[HH];
#pragma unroll
    for (int h = 0; h < HH; ++h) acc[h] = b1n[h];
#pragma unroll
    for (int k = 0; k < KK; ++k)
#pragma unroll
        for (int h = 0; h < HH; ++h)
            acc[h] = fmaf(s[k], W1n[k * HH + h], acc[h]);

    float z = b2[n];
#pragma unroll
    for (int h = 0; h < HH; ++h)
        z = fmaf(fmaxf(acc[h], 0.0f), W2n[h], z);
    outp[(size_t)b * NN + n] = 1.0f / (1.0f + __expf(-z));
}

extern "C" void kernel_launch(void* const* d_in, const int* in_sizes, int n_in,
                              void* d_out, int out_size, void* d_ws, size_t ws_size,
                              hipStream_t stream) {
    const float* x      = (const float*)d_in[0];
    const int*   neighs = (const int*)d_in[1];
    const float* W1     = (const float*)d_in[2];
    const float* b1     = (const float*)d_in[3];
    const float* W2     = (const float*)d_in[4];
    const float* b2     = (const float*)d_in[5];
    float* out = (float*)d_out;

    const size_t pack_bytes = (size_t)NN * 16 * sizeof(uint32_t);  // 512 KB
    const size_t w1f_bytes  = (size_t)NN * 64 * sizeof(uint2);     // 4 MB

    if (ws_size >= pack_bytes + w1f_bytes) {
        uint32_t* xpT = (uint32_t*)d_ws;
        uint2* W1f    = (uint2*)((char*)d_ws + pack_bytes);

        void* kargs[] = {(void*)&x, (void*)&neighs, (void*)&W1, (void*)&b1,
                         (void*)&W2, (void*)&b2, (void*)&xpT, (void*)&out};
        hipError_t e = hipLaunchCooperativeKernel(
            (const void*)fused_kernel, dim3(1024), dim3(512), kargs, 0, stream);
        if (e != hipSuccess) {
            // fallback: two-kernel R7 path
            prep_kernel<<<512 + NN / 4, 256, 0, stream>>>(x, W1, xpT, W1f);
            mfma_kernel<<<dim3(NN / 16, BB / 256), 512, 0, stream>>>(
                xpT, W1f, neighs, b1, W2, b2, out);
        }
    } else {
        scalar_kernel<<<NN, BB, 0, stream>>>(x, neighs, W1, b1, W2, b2, out);
    }
}

// Round 9
// 26.254 us; speedup vs baseline: 5.7378x; 5.7378x over previous
//
#include <hip/hip_runtime.h>
#include <stdint.h>

#define BB 512
#define NN 8192
#define KK 16
#define HH 16

typedef _Float16 f16;
typedef _Float16 f16x4 __attribute__((ext_vector_type(4)));
typedef float f32x4 __attribute__((ext_vector_type(4)));

// ---------------------------------------------------------------------------
// Kernel 1: pack signs of x (+-1) into transposed-word bitmask.
// xpT[j*16+w] bit i = (x[(w*32+i)*N+j] > 0).  512 KB, L2-resident.
// 256 blocks x 512 thr: coalesced x reads (32 consecutive j per lane group),
// LDS-staged so the xpT write is one contiguous 2 KB burst per block.
// ---------------------------------------------------------------------------
__global__ __launch_bounds__(512) void pack_kernel(const float* __restrict__ x,
                                                   uint32_t* __restrict__ xpT) {
    __shared__ uint32_t pstage[32 * 17];
    const int tid = threadIdx.x;
    const int j0  = blockIdx.x * 32;
    const int jl  = tid & 31;   // 32 consecutive j -> 128B coalesced reads
    const int wq  = tid >> 5;   // word group 0..15
    uint32_t word = 0u;
#pragma unroll
    for (int i = 0; i < 32; ++i)
        word |= (x[(size_t)(wq * 32 + i) * NN + j0 + jl] > 0.0f ? 1u : 0u) << i;
    pstage[jl * 17 + wq] = word;
    __syncthreads();
    // contiguous 2KB write: xpT[j0*16 .. j0*16+512)
    xpT[(size_t)j0 * 16 + tid] = pstage[(tid >> 4) * 17 + (tid & 15)];
}

// ---------------------------------------------------------------------------
// Kernel 2: grid (512,2); block = 16n x 256b, 512 thr = 8 waves;
// wave = 2n x 256b = 32 MFMAs.  W1 slice (16 KB) staged raw -> LDS (two
// float4 loads/thread, overlapping neighs/xpT gather latency); f16 A-frags
// built in-register from LDS (W1f global round-trip eliminated).  Sign
// words in wave-private LDS wbuf [w][k] stride 20; B-frag = bit -> +-1.0f16
// via shift/xor into 0xBC00BC00; mfma_f32_16x16x16_f16 (K=16 exact).
// Per MFMA: 8-op relu-dot -> zbuf; per 4-tile group one dense pass
// (64 lanes = 64 outputs, rcpf(1+expf), no shfl/no fp32 div).  Output
// transpose fused via LDS tile (union w/ w1s); full-64B-line stores.
// LDS 33.8 KB -> 4 blocks/CU, 8 waves/SIMD at <=64 VGPR.
// ---------------------------------------------------------------------------
__global__ __launch_bounds__(512, 8) void mfma_kernel(
    const uint32_t* __restrict__ xpT, const float* __restrict__ W1,
    const int* __restrict__ neighs, const float* __restrict__ b1,
    const float* __restrict__ W2, const float* __restrict__ b2,
    float* __restrict__ out) {
    __shared__ __align__(16) union SMem {
        float w1s[16 * 256];    // W1 slice (prologue)
        float tile[256 * 20];   // output transpose tile (epilogue)
    } usm;
    __shared__ __align__(16) uint32_t wbuf[8][8 * 20];  // [wave][w*20+k]
    __shared__ __align__(16) float zbuf[8][64][4];      // [wave][t*16+b16][lg]

    const int tid = threadIdx.x;
    const int wv  = tid >> 6;        // 0..7
    const int l   = tid & 63;
    const int l15 = l & 15;
    const int lg  = l >> 4;          // 0..3
    const int n0  = blockIdx.x * 16;
    const int b0  = blockIdx.y * 256;
    const int w0  = blockIdx.y * 8;  // word base for this b-half

    const int nA = n0 + wv * 2;
    const int nB = nA + 1;

    // ---- issue all independent global loads up front ----
    const float4* w1src = (const float4*)(W1 + (size_t)n0 * (KK * HH));
    const float4 w1a = w1src[tid];
    const float4 w1b = w1src[tid + 512];
    const int j0g = neighs[nA * KK + l15];   // 64B broadcast loads
    const int j1g = neighs[nB * KK + l15];
    const float4 b1v0 = *(const float4*)(b1 + (size_t)nA * HH + lg * 4);
    const float4 b1v1 = *(const float4*)(b1 + (size_t)nB * HH + lg * 4);
    const float4 w2v0 = *(const float4*)(W2 + (size_t)nA * HH + lg * 4);
    const float4 w2v1 = *(const float4*)(W2 + (size_t)nB * HH + lg * 4);
    const float b2n0 = b2[nA];
    const float b2n1 = b2[nB];

    // gathers depend only on j -> issue as soon as possible
    const uint2 g0 = *(const uint2*)&xpT[(size_t)j0g * 16 + w0 + lg * 2];
    const uint2 g1 = *(const uint2*)&xpT[(size_t)j1g * 16 + w0 + lg * 2];

    // ---- stage W1 slice, build A-frags ----
    ((float4*)usm.w1s)[tid]       = w1a;
    ((float4*)usm.w1s)[tid + 512] = w1b;
    __syncthreads();
    f16x4 aA, aB;
#pragma unroll
    for (int i = 0; i < 4; ++i)
        aA[i] = (f16)usm.w1s[(wv * 2) * 256 + (lg * 4 + i) * 16 + l15];
#pragma unroll
    for (int i = 0; i < 4; ++i)
        aB[i] = (f16)usm.w1s[(wv * 2 + 1) * 256 + (lg * 4 + i) * 16 + l15];
    __syncthreads();   // w1s dead -> tile may be written

#pragma unroll
    for (int ni = 0; ni < 2; ++ni) {
        const uint2 g = ni ? g1 : g0;
        const f16x4 a = ni ? aB : aA;
        const float4 b1v = ni ? b1v1 : b1v0;
        const float4 w2v = ni ? w2v1 : w2v0;
        const float b2n  = ni ? b2n1 : b2n0;
        const f32x4 cinit = {b1v.x, b1v.y, b1v.z, b1v.w};
        const int nloc = wv * 2 + ni;

        // stage this ni's sign words (wave-private, no barrier)
        wbuf[wv][(2 * lg) * 20 + l15]     = g.x;
        wbuf[wv][(2 * lg + 1) * 20 + l15] = g.y;

#pragma unroll
        for (int g4 = 0; g4 < 4; ++g4) {   // 4 groups x 4 tiles
#pragma unroll
            for (int t = 0; t < 4; ++t) {
                const int tb = g4 * 4 + t;
                const int wg = tb >> 1;
                const uint4 wk = *(const uint4*)&wbuf[wv][wg * 20 + lg * 4];
                const int pos = (tb & 1) * 16 + l15;
                // bit=1 -> +1.0f16 (0x3C00), bit=0 -> -1.0f16 (0xBC00)
                const uint32_t d0 = 0xBC00BC00u ^ (((wk.x >> pos) & 1u) << 15) ^
                                    ((wk.y >> pos) << 31);
                const uint32_t d1 = 0xBC00BC00u ^ (((wk.z >> pos) & 1u) << 15) ^
                                    ((wk.w >> pos) << 31);
                uint2 bdu; bdu.x = d0; bdu.y = d1;
                const f16x4 bfr = __builtin_bit_cast(f16x4, bdu);

                const f32x4 acc = __builtin_amdgcn_mfma_f32_16x16x16f16(
                    a, bfr, cinit, 0, 0, 0);

                const float zp =
                    fmaf(fmaxf(acc[0], 0.f), w2v.x,
                    fmaf(fmaxf(acc[1], 0.f), w2v.y,
                    fmaf(fmaxf(acc[2], 0.f), w2v.z,
                         fmaxf(acc[3], 0.f) * w2v.w)));
                zbuf[wv][t * 16 + l15][lg] = zp;
            }
            // dense pass: 64 lanes = 64 outputs of this 4-tile group
            const f32x4 v = *(const f32x4*)&zbuf[wv][l][0];
            const float z = (v[0] + v[1]) + (v[2] + v[3]) + b2n;
            const float r = __builtin_amdgcn_rcpf(1.0f + __expf(-z));
            usm.tile[(g4 * 64 + l) * 20 + nloc] = r;
        }
    }
    __syncthreads();

    // full-line stores: 4 lanes cover one 64B row of out[b][n0..n0+15]
#pragma unroll
    for (int p = 0; p < 2; ++p) {
        const int row = (tid >> 2) + p * 128;
        const int c   = (tid & 3) * 4;
        const float4 v = *(const float4*)&usm.tile[row * 20 + c];
        *(float4*)(out + (size_t)(b0 + row) * NN + n0 + c) = v;
    }
}

// ---------------------------------------------------------------------------
// Fallback scalar kernel (only if workspace is too small).
// ---------------------------------------------------------------------------
__global__ __launch_bounds__(512) void scalar_kernel(
    const float* __restrict__ x, const int* __restrict__ neighs,
    const float* __restrict__ W1, const float* __restrict__ b1,
    const float* __restrict__ W2, const float* __restrict__ b2,
    float* __restrict__ outp) {
    const int n = blockIdx.x;
    const int b = threadIdx.x;
    const int* nb = neighs + n * KK;
    const float* W1n = W1 + (size_t)n * KK * HH;
    const float* b1n = b1 + (size_t)n * HH;
    const float* W2n = W2 + (size_t)n * HH;

    float s[KK];
#pragma unroll
    for (int k = 0; k < KK; ++k) s[k] = x[(size_t)b * NN + nb[k]];

    float acc[HH];
#pragma unroll
    for (int h = 0; h < HH; ++h) acc[h] = b1n[h];
#pragma unroll
    for (int k = 0; k < KK; ++k)
#pragma unroll
        for (int h = 0; h < HH; ++h)
            acc[h] = fmaf(s[k], W1n[k * HH + h], acc[h]);

    float z = b2[n];
#pragma unroll
    for (int h = 0; h < HH; ++h)
        z = fmaf(fmaxf(acc[h], 0.0f), W2n[h], z);
    outp[(size_t)b * NN + n] = 1.0f / (1.0f + __expf(-z));
}

extern "C" void kernel_launch(void* const* d_in, const int* in_sizes, int n_in,
                              void* d_out, int out_size, void* d_ws, size_t ws_size,
                              hipStream_t stream) {
    const float* x      = (const float*)d_in[0];
    const int*   neighs = (const int*)d_in[1];
    const float* W1     = (const float*)d_in[2];
    const float* b1     = (const float*)d_in[3];
    const float* W2     = (const float*)d_in[4];
    const float* b2     = (const float*)d_in[5];
    float* out = (float*)d_out;

    const size_t pack_bytes = (size_t)NN * 16 * sizeof(uint32_t);  // 512 KB

    if (ws_size >= pack_bytes) {
        uint32_t* xpT = (uint32_t*)d_ws;
        pack_kernel<<<NN / 32, 512, 0, stream>>>(x, xpT);
        mfma_kernel<<<dim3(NN / 16, BB / 256), 512, 0, stream>>>(
            xpT, W1, neighs, b1, W2, b2, out);
    } else {
        scalar_kernel<<<NN, BB, 0, stream>>>(x, neighs, W1, b1, W2, b2, out);
    }
}

// Round 10
// 25.378 us; speedup vs baseline: 5.9359x; 1.0345x over previous
//
#include <hip/hip_runtime.h>
#include <stdint.h>

#define BB 512
#define NN 8192
#define KK 16
#define HH 16

typedef _Float16 f16;
typedef _Float16 f16x4 __attribute__((ext_vector_type(4)));
typedef float f32x4 __attribute__((ext_vector_type(4)));

// ---------------------------------------------------------------------------
// Kernel 1: pack signs of x (+-1) into transposed-word bitmask.
// xpT[j*16+w] bit i = (x[(w*32+i)*N+j] > 0).  512 KB, L2-resident.
// 256 blocks x 512 thr: coalesced x reads, LDS-staged contiguous 2KB write.
// ---------------------------------------------------------------------------
__global__ __launch_bounds__(512) void pack_kernel(const float* __restrict__ x,
                                                   uint32_t* __restrict__ xpT) {
    __shared__ uint32_t pstage[32 * 17];
    const int tid = threadIdx.x;
    const int j0  = blockIdx.x * 32;
    const int jl  = tid & 31;   // 32 consecutive j -> 128B coalesced reads
    const int wq  = tid >> 5;   // word group 0..15
    uint32_t word = 0u;
#pragma unroll
    for (int i = 0; i < 32; ++i)
        word |= (x[(size_t)(wq * 32 + i) * NN + j0 + jl] > 0.0f ? 1u : 0u) << i;
    pstage[jl * 17 + wq] = word;
    __syncthreads();
    xpT[(size_t)j0 * 16 + tid] = pstage[(tid >> 4) * 17 + (tid & 15)];
}

// ---------------------------------------------------------------------------
// Kernel 2: grid (1024,2) = 2048 blocks -> 2 generations at 4 blocks/CU
// (gen-2 prologue hides under gen-1 compute).  Block = 8n x 256b, 512 thr =
// 8 waves; wave = exactly 1 n (self-contained, NO prologue barriers).
// Per wave: A-frag from 4 strided W1 loads + cvt (L2-served, no LDS stage);
// sign-word gather (uint2/lane, 4 lanes share one xpT row -> 32B contiguous);
// words in wave-private LDS wbuf (lgkmcnt-ordered, no __syncthreads);
// B-frag = bit -> +-1.0f16 via shift/xor into 0xBC00BC00;
// mfma_f32_16x16x16_f16 (K=16 exact); 8-op relu-dot -> zbuf; per 4-tile
// group one dense pass (64 lanes = 64 outputs, rcpf(1+expf)).  Output
// transpose via tile[256][12]; single __syncthreads before the store.
// LDS 25.6 KB; ~40 VGPR -> 8 waves/SIMD, no spill.
// ---------------------------------------------------------------------------
__global__ __launch_bounds__(512, 8) void mfma_kernel(
    const uint32_t* __restrict__ xpT, const float* __restrict__ W1,
    const int* __restrict__ neighs, const float* __restrict__ b1,
    const float* __restrict__ W2, const float* __restrict__ b2,
    float* __restrict__ out) {
    __shared__ __align__(16) uint32_t wbuf[8][8 * 20];  // [wave][w*20+k]
    __shared__ __align__(16) float zbuf[8][64][4];      // [wave][t*16+b16][lg]
    __shared__ __align__(16) float tile[256 * 12];      // [b_local][n_local]

    const int tid = threadIdx.x;
    const int wv  = tid >> 6;        // 0..7  (= n_local)
    const int l   = tid & 63;
    const int l15 = l & 15;
    const int lg  = l >> 4;          // 0..3
    const int n0  = blockIdx.x * 8;
    const int b0  = blockIdx.y * 256;
    const int w0  = blockIdx.y * 8;  // word base for this b-half

    const int n = n0 + wv;

    // ---- issue all independent global loads up front (no barriers) ----
    const int j = neighs[n * KK + l15];                  // 64B broadcast
    const uint2 g = *(const uint2*)&xpT[(size_t)j * 16 + w0 + lg * 2];
    const float* W1n = W1 + (size_t)n * (KK * HH) + lg * 4 * HH + l15;
    const float a0 = W1n[0 * HH];
    const float a1 = W1n[1 * HH];
    const float a2 = W1n[2 * HH];
    const float a3 = W1n[3 * HH];
    const float4 b1v = *(const float4*)(b1 + (size_t)n * HH + lg * 4);
    const float4 w2v = *(const float4*)(W2 + (size_t)n * HH + lg * 4);
    const float b2n = b2[n];

    const f16x4 a = {(f16)a0, (f16)a1, (f16)a2, (f16)a3};
    const f32x4 cinit = {b1v.x, b1v.y, b1v.z, b1v.w};

    // ---- stage sign words to wave-private LDS (lgkmcnt-ordered) ----
    wbuf[wv][(2 * lg) * 20 + l15]     = g.x;
    wbuf[wv][(2 * lg + 1) * 20 + l15] = g.y;

#pragma unroll
    for (int g4 = 0; g4 < 4; ++g4) {   // 4 groups x 4 tiles of 16 b
#pragma unroll
        for (int t = 0; t < 4; ++t) {
            const int tb = g4 * 4 + t;
            const int wg = tb >> 1;
            const uint4 wk = *(const uint4*)&wbuf[wv][wg * 20 + lg * 4];
            const int pos = (tb & 1) * 16 + l15;  // bit index within word
            // bit=1 -> +1.0f16 (0x3C00), bit=0 -> -1.0f16 (0xBC00)
            const uint32_t d0 = 0xBC00BC00u ^ (((wk.x >> pos) & 1u) << 15) ^
                                ((wk.y >> pos) << 31);
            const uint32_t d1 = 0xBC00BC00u ^ (((wk.z >> pos) & 1u) << 15) ^
                                ((wk.w >> pos) << 31);
            uint2 bdu; bdu.x = d0; bdu.y = d1;
            const f16x4 bfr = __builtin_bit_cast(f16x4, bdu);

            const f32x4 acc = __builtin_amdgcn_mfma_f32_16x16x16f16(
                a, bfr, cinit, 0, 0, 0);

            // relu-dot partial: zp(lg, b=l15)
            const float zp =
                fmaf(fmaxf(acc[0], 0.f), w2v.x,
                fmaf(fmaxf(acc[1], 0.f), w2v.y,
                fmaf(fmaxf(acc[2], 0.f), w2v.z,
                     fmaxf(acc[3], 0.f) * w2v.w)));
            zbuf[wv][t * 16 + l15][lg] = zp;
        }
        // dense pass: 64 lanes = 64 outputs of this 4-tile group
        const f32x4 v = *(const f32x4*)&zbuf[wv][l][0];
        const float z = (v[0] + v[1]) + (v[2] + v[3]) + b2n;
        const float r = __builtin_amdgcn_rcpf(1.0f + __expf(-z));
        tile[(g4 * 64 + l) * 12 + wv] = r;
    }
    __syncthreads();

    // stores: 2 lanes cover one 32B half-row of out[b][n0..n0+7]
    const int row = tid >> 1;
    const int c   = (tid & 1) * 4;
    const float4 v = *(const float4*)&tile[row * 12 + c];
    *(float4*)(out + (size_t)(b0 + row) * NN + n0 + c) = v;
}

// ---------------------------------------------------------------------------
// Fallback scalar kernel (only if workspace is too small).
// ---------------------------------------------------------------------------
__global__ __launch_bounds__(512) void scalar_kernel(
    const float* __restrict__ x, const int* __restrict__ neighs,
    const float* __restrict__ W1, const float* __restrict__ b1,
    const float* __restrict__ W2, const float* __restrict__ b2,
    float* __restrict__ outp) {
    const int n = blockIdx.x;
    const int b = threadIdx.x;
    const int* nb = neighs + n * KK;
    const float* W1n = W1 + (size_t)n * KK * HH;
    const float* b1n = b1 + (size_t)n * HH;
    const float* W2n = W2 + (size_t)n * HH;

    float s[KK];
#pragma unroll
    for (int k = 0; k < KK; ++k) s[k] = x[(size_t)b * NN + nb[k]];

    float acc[HH];
#pragma unroll
    for (int h = 0; h < HH; ++h) acc[h] = b1n[h];
#pragma unroll
    for (int k = 0; k < KK; ++k)
#pragma unroll
        for (int h = 0; h < HH; ++h)
            acc[h] = fmaf(s[k], W1n[k * HH + h], acc[h]);

    float z = b2[n];
#pragma unroll
    for (int h = 0; h < HH; ++h)
        z = fmaf(fmaxf(acc[h], 0.0f), W2n[h], z);
    outp[(size_t)b * NN + n] = 1.0f / (1.0f + __expf(-z));
}

extern "C" void kernel_launch(void* const* d_in, const int* in_sizes, int n_in,
                              void* d_out, int out_size, void* d_ws, size_t ws_size,
                              hipStream_t stream) {
    const float* x      = (const float*)d_in[0];
    const int*   neighs = (const int*)d_in[1];
    const float* W1     = (const float*)d_in[2];
    const float* b1     = (const float*)d_in[3];
    const float* W2     = (const float*)d_in[4];
    const float* b2     = (const float*)d_in[5];
    float* out = (float*)d_out;

    const size_t pack_bytes = (size_t)NN * 16 * sizeof(uint32_t);  // 512 KB

    if (ws_size >= pack_bytes) {
        uint32_t* xpT = (uint32_t*)d_ws;
        pack_kernel<<<NN / 32, 512, 0, stream>>>(x, xpT);
        mfma_kernel<<<dim3(NN / 8, BB / 256), 512, 0, stream>>>(
            xpT, W1, neighs, b1, W2, b2, out);
    } else {
        scalar_kernel<<<NN, BB, 0, stream>>>(x, neighs, W1, b1, W2, b2, out);
    }
}